// Round 1
// baseline (3447.781 us; speedup 1.0000x reference)
//
#include <hip/hip_runtime.h>

// ---------------------------------------------------------------------------
// Problem: B=128, T=256, N=512, M=512.
// Key algebraic fact: softmax over a constant row == uniform 1/N, so the whole
// "attention" arm (W_e, U_e, e, alpha) is dead code. The op is an LSTM with
// inputs scaled by 1/512.
//   xg[b,t,j] = sum_n x[b,t,n]/512 * w_ih[j,n] + b_ih[j] + b_hh[j]   (parallel GEMM)
//   per step:  gates = xg[:,t,:] + h @ w_hh^T ; standard LSTM cell; out = h
// ---------------------------------------------------------------------------

typedef __attribute__((ext_vector_type(8))) __bf16 bf16x8;
typedef __attribute__((ext_vector_type(8))) unsigned short u16x8;
typedef __attribute__((ext_vector_type(4))) float f32x4;
typedef unsigned short ushort_t;

__device__ __forceinline__ unsigned short f2b(float f) {
  // round-to-nearest-even fp32 -> bf16 (finite inputs)
  unsigned u = __builtin_bit_cast(unsigned, f);
  unsigned r = (u + 0x7FFFu + ((u >> 16) & 1u)) >> 16;
  return (unsigned short)r;
}
__device__ __forceinline__ float b2f(unsigned short s) {
  unsigned u = ((unsigned)s) << 16;
  return __builtin_bit_cast(float, u);
}
__device__ __forceinline__ float sigm(float x) { return 1.0f / (1.0f + __expf(-x)); }
__device__ __forceinline__ float tanh_f(float x) { return 1.0f - 2.0f / (__expf(2.0f * x) + 1.0f); }

// ---------------------------------------------------------------------------
// Kernel 1: convert inputs -> bf16 (scaled by 1/512), w_ih -> bf16, bias sum.
// ---------------------------------------------------------------------------
__global__ __launch_bounds__(256) void convert_kernel(
    const float* __restrict__ inp, const float* __restrict__ wih,
    const float* __restrict__ bih, const float* __restrict__ bhh,
    ushort_t* __restrict__ X, ushort_t* __restrict__ W, float* __restrict__ bias)
{
  int tid = blockIdx.x * 256 + threadIdx.x;
  int stride = gridDim.x * 256;
  const float s = 1.0f / 512.0f;
  for (int i = tid; i < (16777216 / 4); i += stride) {
    float4 v = reinterpret_cast<const float4*>(inp)[i];
    ushort4 o; o.x = f2b(v.x * s); o.y = f2b(v.y * s); o.z = f2b(v.z * s); o.w = f2b(v.w * s);
    reinterpret_cast<ushort4*>(X)[i] = o;
  }
  for (int i = tid; i < (1048576 / 4); i += stride) {
    float4 v = reinterpret_cast<const float4*>(wih)[i];
    ushort4 o; o.x = f2b(v.x); o.y = f2b(v.y); o.z = f2b(v.z); o.w = f2b(v.w);
    reinterpret_cast<ushort4*>(W)[i] = o;
  }
  for (int i = tid; i < 2048; i += stride) bias[i] = bih[i] + bhh[i];
}

// ---------------------------------------------------------------------------
// Kernel 2: xg GEMM. C[32768,2048] = X[32768,512](bf16) @ W[2048,512]^T + bias.
// 128x128 tile, BK=64, 4 waves (2x2), 16x16x32 bf16 MFMA.
// LDS XOR-swizzled (chunk ^= row&7) against stride-128B bank conflicts.
// A/B fragments use identical k-index math -> internal k-permutation cancels.
// ---------------------------------------------------------------------------
template<bool XGBF>
__global__ __launch_bounds__(256) void gemm_xg_kernel(
    const ushort_t* __restrict__ X, const ushort_t* __restrict__ W,
    const float* __restrict__ bias, void* __restrict__ xg)
{
  __shared__ bf16x8 AsV[1024];   // 128 rows x 64 bf16 = 16 KB
  __shared__ bf16x8 BsV[1024];
  ushort_t* As = (ushort_t*)AsV;
  ushort_t* Bs = (ushort_t*)BsV;

  int tid = threadIdx.x;
  int lane = tid & 63;
  int wv = tid >> 6;
  int wr = wv >> 1, wc = wv & 1;     // wave 2x2 over (rows, cols)
  int ll = lane & 15;                // fragment row/col within 16
  int kg = lane >> 4;                // k-group 0..3
  int bm = blockIdx.x & 255;         // 256 M-blocks (fast-varying: shares B tile)
  int bn = blockIdx.x >> 8;          // 16 N-blocks

  f32x4 acc[4][4];
#pragma unroll
  for (int i = 0; i < 4; ++i)
#pragma unroll
    for (int j = 0; j < 4; ++j) acc[i][j] = (f32x4){0.f, 0.f, 0.f, 0.f};

  for (int kt = 0; kt < 8; ++kt) {
#pragma unroll
    for (int it = 0; it < 4; ++it) {
      int i = it * 256 + tid;        // 0..1023 chunk ids (row=i>>3, 16B chunk=i&7)
      int row = i >> 3, ch = i & 7;
      int de = row * 64 + ((ch ^ (row & 7)) << 3);
      *reinterpret_cast<bf16x8*>(As + de) =
          *reinterpret_cast<const bf16x8*>(X + (size_t)(bm * 128 + row) * 512 + kt * 64 + ch * 8);
      *reinterpret_cast<bf16x8*>(Bs + de) =
          *reinterpret_cast<const bf16x8*>(W + (size_t)(bn * 128 + row) * 512 + kt * 64 + ch * 8);
    }
    __syncthreads();
#pragma unroll
    for (int kc = 0; kc < 2; ++kc) {
      int kch = kc * 4 + kg;         // 16B-chunk index within row (0..7)
      bf16x8 a[4], b[4];
#pragma unroll
      for (int fi = 0; fi < 4; ++fi) {
        int row = wr * 64 + fi * 16 + ll;
        a[fi] = *reinterpret_cast<const bf16x8*>(As + row * 64 + ((kch ^ (row & 7)) << 3));
      }
#pragma unroll
      for (int fj = 0; fj < 4; ++fj) {
        int row = wc * 64 + fj * 16 + ll;
        b[fj] = *reinterpret_cast<const bf16x8*>(Bs + row * 64 + ((kch ^ (row & 7)) << 3));
      }
#pragma unroll
      for (int fi = 0; fi < 4; ++fi)
#pragma unroll
        for (int fj = 0; fj < 4; ++fj)
          acc[fi][fj] = __builtin_amdgcn_mfma_f32_16x16x32_bf16(a[fi], b[fj], acc[fi][fj], 0, 0, 0);
    }
    __syncthreads();
  }
  // epilogue: + bias, store (verified C/D map: col=lane&15, row=(lane>>4)*4+r)
#pragma unroll
  for (int fj = 0; fj < 4; ++fj) {
    int colj = bn * 128 + wc * 64 + fj * 16 + ll;
    float bv = bias[colj];
#pragma unroll
    for (int fi = 0; fi < 4; ++fi)
#pragma unroll
      for (int r = 0; r < 4; ++r) {
        int rowi = bm * 128 + wr * 64 + fi * 16 + kg * 4 + r;
        float v = acc[fi][fj][r] + bv;
        if constexpr (XGBF) ((ushort_t*)xg)[(size_t)rowi * 2048 + colj] = f2b(v);
        else                ((float*)xg)[(size_t)rowi * 2048 + colj] = v;
      }
  }
}

// ---------------------------------------------------------------------------
// Kernel 3: persistent LSTM recurrence.
// Grid = 64 wgs: gb in 0..3 (32 batches each) x gm in 0..15 (32 m each).
// 4 waves (2x2 over b,m): wave tile = 16 b x 16 m x 4 gates.
// w_hh fragments live ENTIRELY in VGPRs (bf16x8 bfr[4][16] = 256 VGPR/lane,
// __launch_bounds__(256,1) -> 512 budget). Zero LDS in the loop.
// h double-buffered bf16 in ws; c in registers; per-b-group atomic barrier
// (monotonic counter, 16 wgs/group) with agent-scope release/acquire fences
// for cross-XCD visibility. 64 small wgs << 256 CUs -> co-resident.
// ---------------------------------------------------------------------------
template<bool XGBF>
__global__ __launch_bounds__(256, 1) void lstm_rec_kernel(
    const float* __restrict__ whh, const void* __restrict__ xg,
    ushort_t* __restrict__ hbuf /*[2][128][512] bf16*/, float* __restrict__ out,
    unsigned* __restrict__ bars)
{
  int tid = threadIdx.x;
  int lane = tid & 63;
  int wv = tid >> 6;
  int wvb = wv >> 1, wvm = wv & 1;
  int gb = blockIdx.x >> 4;   // 0..3  batch group
  int gm = blockIdx.x & 15;   // 0..15 m group
  int ll = lane & 15, kg = lane >> 4;
  int b0 = gb * 32 + wvb * 16;
  int m0 = gm * 32 + wvm * 16;

  // preload w_hh fragments -> registers (fp32 global read once, cvt to bf16)
  bf16x8 bfr[4][16];
#pragma unroll
  for (int g = 0; g < 4; ++g) {
    const float* wrow = whh + (size_t)(g * 512 + m0 + ll) * 512;
#pragma unroll
    for (int ks = 0; ks < 16; ++ks) {
      const float4* wp = reinterpret_cast<const float4*>(wrow + ks * 32 + kg * 8);
      float4 lo = wp[0], hi = wp[1];
      u16x8 tbits;
      tbits[0] = f2b(lo.x); tbits[1] = f2b(lo.y); tbits[2] = f2b(lo.z); tbits[3] = f2b(lo.w);
      tbits[4] = f2b(hi.x); tbits[5] = f2b(hi.y); tbits[6] = f2b(hi.z); tbits[7] = f2b(hi.w);
      bfr[g][ks] = __builtin_bit_cast(bf16x8, tbits);
    }
  }

  float c[4] = {0.f, 0.f, 0.f, 0.f};
  unsigned* bar = bars + gb * 32;  // 128 B apart per group

  for (int t = 0; t < 256; ++t) {
    // prefetch xg for this step (independent of h -> hides HBM latency)
    float xv[4][4];
#pragma unroll
    for (int g = 0; g < 4; ++g)
#pragma unroll
      for (int r = 0; r < 4; ++r) {
        size_t idx = ((size_t)(b0 + kg * 4 + r) * 256 + t) * 2048 + (size_t)g * 512 + m0 + ll;
        if constexpr (XGBF) xv[g][r] = b2f(((const ushort_t*)xg)[idx]);
        else                xv[g][r] = ((const float*)xg)[idx];
      }

    const ushort_t* hread = hbuf + (size_t)(t & 1) * 65536;
    f32x4 acc[4];
#pragma unroll
    for (int g = 0; g < 4; ++g) acc[g] = (f32x4){0.f, 0.f, 0.f, 0.f};
#pragma unroll
    for (int ks = 0; ks < 16; ++ks) {
      bf16x8 a = *reinterpret_cast<const bf16x8*>(hread + (size_t)(b0 + ll) * 512 + ks * 32 + kg * 8);
#pragma unroll
      for (int g = 0; g < 4; ++g)
        acc[g] = __builtin_amdgcn_mfma_f32_16x16x32_bf16(a, bfr[g][ks], acc[g], 0, 0, 0);
    }

    ushort_t* hwrite = hbuf + (size_t)((t + 1) & 1) * 65536;
#pragma unroll
    for (int r = 0; r < 4; ++r) {
      int b = b0 + kg * 4 + r;
      int m = m0 + ll;
      float ig = sigm(acc[0][r] + xv[0][r]);
      float fg = sigm(acc[1][r] + xv[1][r]);
      float gg = tanh_f(acc[2][r] + xv[2][r]);
      float og = sigm(acc[3][r] + xv[3][r]);
      c[r] = fg * c[r] + ig * gg;
      float h = og * tanh_f(c[r]);
      __builtin_nontemporal_store(h, out + ((size_t)b * 256 + t) * 512 + m);
      hwrite[(size_t)b * 512 + m] = f2b(h);
    }

    if (t < 255) {
      __builtin_amdgcn_fence(__ATOMIC_RELEASE, "agent");  // flush h stores
      __syncthreads();
      if (tid == 0) {
        __hip_atomic_fetch_add(bar, 1u, __ATOMIC_RELEASE, __HIP_MEMORY_SCOPE_AGENT);
        unsigned tgt = 16u * (unsigned)(t + 1);
        while (__hip_atomic_load(bar, __ATOMIC_ACQUIRE, __HIP_MEMORY_SCOPE_AGENT) < tgt)
          __builtin_amdgcn_s_sleep(2);
      }
      __syncthreads();
      __builtin_amdgcn_fence(__ATOMIC_ACQUIRE, "agent");  // invalidate L1/L2 for h reads
    }
  }
}

// ---------------------------------------------------------------------------
extern "C" void kernel_launch(void* const* d_in, const int* in_sizes, int n_in,
                              void* d_out, int out_size, void* d_ws, size_t ws_size,
                              hipStream_t stream)
{
  const float* inputs = (const float*)d_in[0];
  // d_in[1..3] = W_e_w, W_e_b, U_e_w : dead code (softmax of a constant row)
  const float* w_ih = (const float*)d_in[4];
  const float* w_hh = (const float*)d_in[5];
  const float* b_ih = (const float*)d_in[6];
  const float* b_hh = (const float*)d_in[7];
  float* out = (float*)d_out;
  char* ws = (char*)d_ws;

  const size_t xg_f32_bytes = (size_t)32768 * 2048 * 4;  // 268 MB
  const size_t xg_bf_bytes  = (size_t)32768 * 2048 * 2;  // 134 MB
  const size_t xbytes = (size_t)16777216 * 2;            // X bf16
  const size_t wbytes = (size_t)1048576 * 2;             // w_ih bf16
  const size_t biasb  = 2048 * 4;
  const size_t hbytes = (size_t)2 * 128 * 512 * 2;       // h double buffer
  const size_t barb   = 512;
  const size_t tail = xbytes + wbytes + biasb + hbytes + barb + 1024;

  bool f32p = ws_size >= xg_f32_bytes + tail;            // adaptive xg precision
  size_t xgb  = f32p ? xg_f32_bytes : xg_bf_bytes;
  size_t oX   = xgb;
  size_t oW   = oX + xbytes;
  size_t oB   = oW + wbytes;
  size_t oH   = (oB + biasb + 255) & ~(size_t)255;
  size_t oBar = oH + hbytes;

  hipMemsetAsync(ws + oH, 0, hbytes + barb, stream);     // zero h0 + barrier counters

  convert_kernel<<<2048, 256, 0, stream>>>(inputs, w_ih, b_ih, b_hh,
      (ushort_t*)(ws + oX), (ushort_t*)(ws + oW), (float*)(ws + oB));

  if (f32p) {
    gemm_xg_kernel<false><<<4096, 256, 0, stream>>>(
        (const ushort_t*)(ws + oX), (const ushort_t*)(ws + oW), (const float*)(ws + oB), ws);
    lstm_rec_kernel<false><<<64, 256, 0, stream>>>(
        w_hh, ws, (ushort_t*)(ws + oH), out, (unsigned*)(ws + oBar));
  } else {
    gemm_xg_kernel<true><<<4096, 256, 0, stream>>>(
        (const ushort_t*)(ws + oX), (const ushort_t*)(ws + oW), (const float*)(ws + oB), ws);
    lstm_rec_kernel<true><<<64, 256, 0, stream>>>(
        w_hh, ws, (ushort_t*)(ws + oH), out, (unsigned*)(ws + oBar));
  }
  (void)in_sizes; (void)n_in; (void)out_size;
}

// Round 2
// 1364.065 us; speedup vs baseline: 2.5276x; 2.5276x over previous
//
#include <hip/hip_runtime.h>

// ---------------------------------------------------------------------------
// Problem: B=128, T=256, N=512, M=512.
// softmax over a constant row == uniform 1/N => attention arm is dead code.
// Op is an LSTM with inputs scaled by 1/512.
//   xg[b,t,j] = sum_n x[b,t,n]/512 * w_ih[j,n] + b_ih[j] + b_hh[j]   (GEMM)
//   per step:  gates = xg[:,t,:] + h @ w_hh^T ; LSTM cell; out = h
//
// R2 change: the per-step agent fences (buffer_wbl2/buffer_inv = full L2
// flush per wg per step, ~31k cy/step) are replaced by per-access coherent
// h traffic (sc0 sc1 cache bits -> Infinity Cache, which IS coherent) +
// relaxed agent atomics for the barrier + raw s_barrier + counted vmcnt.
// ---------------------------------------------------------------------------

typedef __attribute__((ext_vector_type(8))) __bf16 bf16x8;
typedef __attribute__((ext_vector_type(8))) unsigned short u16x8;
typedef __attribute__((ext_vector_type(4))) float f32x4;
typedef unsigned short ushort_t;

__device__ __forceinline__ unsigned short f2b(float f) {
  unsigned u = __builtin_bit_cast(unsigned, f);
  unsigned r = (u + 0x7FFFu + ((u >> 16) & 1u)) >> 16;
  return (unsigned short)r;
}
__device__ __forceinline__ float b2f(unsigned short s) {
  unsigned u = ((unsigned)s) << 16;
  return __builtin_bit_cast(float, u);
}
__device__ __forceinline__ float sigm(float x) { return 1.0f / (1.0f + __expf(-x)); }
__device__ __forceinline__ float tanh_f(float x) { return 1.0f - 2.0f / (__expf(2.0f * x) + 1.0f); }

#define VMCNT(n) asm volatile("s_waitcnt vmcnt(" #n ")" ::: "memory")

// Coherent (Infinity-Cache-level) accesses: sc0 sc1 bypass L1 and the
// non-coherent per-XCD L2, so no cache-wide fences are needed.
__device__ __forceinline__ void hload16(f32x4* dst, const ushort_t* p) {
  asm volatile("global_load_dwordx4 %0, %1, off sc0 sc1"
               : "=v"(*dst) : "v"(p) : "memory");
}
__device__ __forceinline__ void hstore2(ushort_t* p, unsigned v) {
  asm volatile("global_store_short %0, %1, off sc0 sc1"
               :: "v"(p), "v"(v) : "memory");
}
__device__ __forceinline__ void xload_f32(float* dst, const float* p) {
  asm volatile("global_load_dword %0, %1, off" : "=v"(*dst) : "v"(p) : "memory");
}
__device__ __forceinline__ void xload_bf(unsigned* dst, const ushort_t* p) {
  asm volatile("global_load_ushort %0, %1, off" : "=v"(*dst) : "v"(p) : "memory");
}

// ---------------------------------------------------------------------------
// Kernel 1: convert inputs -> bf16 (scaled 1/512), w_ih -> bf16, bias sum.
// ---------------------------------------------------------------------------
__global__ __launch_bounds__(256) void convert_kernel(
    const float* __restrict__ inp, const float* __restrict__ wih,
    const float* __restrict__ bih, const float* __restrict__ bhh,
    ushort_t* __restrict__ X, ushort_t* __restrict__ W, float* __restrict__ bias)
{
  int tid = blockIdx.x * 256 + threadIdx.x;
  int stride = gridDim.x * 256;
  const float s = 1.0f / 512.0f;
  for (int i = tid; i < (16777216 / 4); i += stride) {
    float4 v = reinterpret_cast<const float4*>(inp)[i];
    ushort4 o; o.x = f2b(v.x * s); o.y = f2b(v.y * s); o.z = f2b(v.z * s); o.w = f2b(v.w * s);
    reinterpret_cast<ushort4*>(X)[i] = o;
  }
  for (int i = tid; i < (1048576 / 4); i += stride) {
    float4 v = reinterpret_cast<const float4*>(wih)[i];
    ushort4 o; o.x = f2b(v.x); o.y = f2b(v.y); o.z = f2b(v.z); o.w = f2b(v.w);
    reinterpret_cast<ushort4*>(W)[i] = o;
  }
  for (int i = tid; i < 2048; i += stride) bias[i] = bih[i] + bhh[i];
}

// ---------------------------------------------------------------------------
// Kernel 2: xg GEMM. C[32768,2048] = X[32768,512](bf16) @ W[2048,512]^T + bias.
// ---------------------------------------------------------------------------
template<bool XGBF>
__global__ __launch_bounds__(256) void gemm_xg_kernel(
    const ushort_t* __restrict__ X, const ushort_t* __restrict__ W,
    const float* __restrict__ bias, void* __restrict__ xg)
{
  __shared__ bf16x8 AsV[1024];
  __shared__ bf16x8 BsV[1024];
  ushort_t* As = (ushort_t*)AsV;
  ushort_t* Bs = (ushort_t*)BsV;

  int tid = threadIdx.x;
  int lane = tid & 63;
  int wv = tid >> 6;
  int wr = wv >> 1, wc = wv & 1;
  int ll = lane & 15;
  int kg = lane >> 4;
  int bm = blockIdx.x & 255;
  int bn = blockIdx.x >> 8;

  f32x4 acc[4][4];
#pragma unroll
  for (int i = 0; i < 4; ++i)
#pragma unroll
    for (int j = 0; j < 4; ++j) acc[i][j] = (f32x4){0.f, 0.f, 0.f, 0.f};

  for (int kt = 0; kt < 8; ++kt) {
#pragma unroll
    for (int it = 0; it < 4; ++it) {
      int i = it * 256 + tid;
      int row = i >> 3, ch = i & 7;
      int de = row * 64 + ((ch ^ (row & 7)) << 3);
      *reinterpret_cast<bf16x8*>(As + de) =
          *reinterpret_cast<const bf16x8*>(X + (size_t)(bm * 128 + row) * 512 + kt * 64 + ch * 8);
      *reinterpret_cast<bf16x8*>(Bs + de) =
          *reinterpret_cast<const bf16x8*>(W + (size_t)(bn * 128 + row) * 512 + kt * 64 + ch * 8);
    }
    __syncthreads();
#pragma unroll
    for (int kc = 0; kc < 2; ++kc) {
      int kch = kc * 4 + kg;
      bf16x8 a[4], b[4];
#pragma unroll
      for (int fi = 0; fi < 4; ++fi) {
        int row = wr * 64 + fi * 16 + ll;
        a[fi] = *reinterpret_cast<const bf16x8*>(As + row * 64 + ((kch ^ (row & 7)) << 3));
      }
#pragma unroll
      for (int fj = 0; fj < 4; ++fj) {
        int row = wc * 64 + fj * 16 + ll;
        b[fj] = *reinterpret_cast<const bf16x8*>(Bs + row * 64 + ((kch ^ (row & 7)) << 3));
      }
#pragma unroll
      for (int fi = 0; fi < 4; ++fi)
#pragma unroll
        for (int fj = 0; fj < 4; ++fj)
          acc[fi][fj] = __builtin_amdgcn_mfma_f32_16x16x32_bf16(a[fi], b[fj], acc[fi][fj], 0, 0, 0);
    }
    __syncthreads();
  }
#pragma unroll
  for (int fj = 0; fj < 4; ++fj) {
    int colj = bn * 128 + wc * 64 + fj * 16 + ll;
    float bv = bias[colj];
#pragma unroll
    for (int fi = 0; fi < 4; ++fi)
#pragma unroll
      for (int r = 0; r < 4; ++r) {
        int rowi = bm * 128 + wr * 64 + fi * 16 + kg * 4 + r;
        float v = acc[fi][fj][r] + bv;
        if constexpr (XGBF) ((ushort_t*)xg)[(size_t)rowi * 2048 + colj] = f2b(v);
        else                ((float*)xg)[(size_t)rowi * 2048 + colj] = v;
      }
  }
}

// ---------------------------------------------------------------------------
// Kernel 3: persistent LSTM recurrence (fence-free coherent protocol).
// 64 wgs = 4 batch-groups x 16 m-groups; 4 waves each; w_hh in VGPRs.
// ---------------------------------------------------------------------------
template<bool XGBF>
__global__ __launch_bounds__(256, 1) void lstm_rec_kernel(
    const float* __restrict__ whh, const void* __restrict__ xg,
    ushort_t* __restrict__ hbuf /*[2][128][512] bf16*/, float* __restrict__ out,
    unsigned* __restrict__ bars)
{
  int tid = threadIdx.x;
  int lane = tid & 63;
  int wv = tid >> 6;
  int wvb = wv >> 1, wvm = wv & 1;
  int gb = blockIdx.x >> 4;
  int gm = blockIdx.x & 15;
  int ll = lane & 15, kg = lane >> 4;
  int b0 = gb * 32 + wvb * 16;
  int m0 = gm * 32 + wvm * 16;

  // preload w_hh fragments -> registers (fp32 read once, cvt to bf16)
  bf16x8 bfr[4][16];
#pragma unroll
  for (int g = 0; g < 4; ++g) {
    const float* wrow = whh + (size_t)(g * 512 + m0 + ll) * 512;
#pragma unroll
    for (int ks = 0; ks < 16; ++ks) {
      const float4* wp = reinterpret_cast<const float4*>(wrow + ks * 32 + kg * 8);
      float4 lo = wp[0], hi = wp[1];
      u16x8 tbits;
      tbits[0] = f2b(lo.x); tbits[1] = f2b(lo.y); tbits[2] = f2b(lo.z); tbits[3] = f2b(lo.w);
      tbits[4] = f2b(hi.x); tbits[5] = f2b(hi.y); tbits[6] = f2b(hi.z); tbits[7] = f2b(hi.w);
      bfr[g][ks] = __builtin_bit_cast(bf16x8, tbits);
    }
  }

  float c[4] = {0.f, 0.f, 0.f, 0.f};
  unsigned* bar = bars + gb * 32;  // 128 B apart per group

  for (int t = 0; t < 256; ++t) {
    const ushort_t* hread = hbuf + (size_t)(t & 1) * 65536;
    const ushort_t* hrow = hread + (size_t)(b0 + ll) * 512 + kg * 8;

    // 1. issue all 16 h-fragment loads (coherent, from Infinity Cache)
    f32x4 hraw[16];
#pragma unroll
    for (int ks = 0; ks < 16; ++ks) hload16(&hraw[ks], hrow + ks * 32);

    // 2. issue 16 xg loads for this step (plain cached loads)
    float xv[4][4];
    unsigned xb[4][4];
#pragma unroll
    for (int g = 0; g < 4; ++g)
#pragma unroll
      for (int r = 0; r < 4; ++r) {
        size_t idx = ((size_t)(b0 + kg * 4 + r) * 256 + t) * 2048 + (size_t)g * 512 + m0 + ll;
        if constexpr (XGBF) xload_bf(&xb[g][r], (const ushort_t*)xg + idx);
        else                xload_f32(&xv[g][r], (const float*)xg + idx);
      }

    f32x4 acc[4];
#pragma unroll
    for (int g = 0; g < 4; ++g) acc[g] = (f32x4){0.f, 0.f, 0.f, 0.f};

    // 3. overlap: first 8 h frags done -> MFMA while rest land.
    //    (in-order vmcnt retirement: stale older ops only make waits stricter)
    VMCNT(24);
    __builtin_amdgcn_sched_barrier(0);
#pragma unroll
    for (int ks = 0; ks < 8; ++ks) {
      bf16x8 a = __builtin_bit_cast(bf16x8, hraw[ks]);
#pragma unroll
      for (int g = 0; g < 4; ++g)
        acc[g] = __builtin_amdgcn_mfma_f32_16x16x32_bf16(a, bfr[g][ks], acc[g], 0, 0, 0);
    }
    VMCNT(16);
    __builtin_amdgcn_sched_barrier(0);
#pragma unroll
    for (int ks = 8; ks < 16; ++ks) {
      bf16x8 a = __builtin_bit_cast(bf16x8, hraw[ks]);
#pragma unroll
      for (int g = 0; g < 4; ++g)
        acc[g] = __builtin_amdgcn_mfma_f32_16x16x32_bf16(a, bfr[g][ks], acc[g], 0, 0, 0);
    }
    VMCNT(0);  // xg loads done
    __builtin_amdgcn_sched_barrier(0);

    // 4. gates + state update; coherent h store
    ushort_t* hwrite = hbuf + (size_t)((t + 1) & 1) * 65536;
    float hv[4];
#pragma unroll
    for (int r = 0; r < 4; ++r) {
      float x0, x1, x2, x3;
      if constexpr (XGBF) { x0 = b2f(xb[0][r]); x1 = b2f(xb[1][r]); x2 = b2f(xb[2][r]); x3 = b2f(xb[3][r]); }
      else                { x0 = xv[0][r]; x1 = xv[1][r]; x2 = xv[2][r]; x3 = xv[3][r]; }
      float ig = sigm(acc[0][r] + x0);
      float fg = sigm(acc[1][r] + x1);
      float gg = tanh_f(acc[2][r] + x2);
      float og = sigm(acc[3][r] + x3);
      c[r] = fg * c[r] + ig * gg;
      hv[r] = og * tanh_f(c[r]);
      hstore2(hwrite + (size_t)(b0 + kg * 4 + r) * 512 + m0 + ll, (unsigned)f2b(hv[r]));
    }

    // 5. drain ONLY the 4 h stores (out stores issued after, overlap barrier)
    VMCNT(0);
#pragma unroll
    for (int r = 0; r < 4; ++r)
      __builtin_nontemporal_store(hv[r], out + ((size_t)(b0 + kg * 4 + r) * 256 + t) * 512 + m0 + ll);

    // 6. group barrier: raw s_barrier (no implicit vmcnt drain) + relaxed
    //    agent atomics (coherent at IF by construction).
    if (t < 255) {
      __builtin_amdgcn_s_barrier();
      if (tid == 0) {
        __hip_atomic_fetch_add(bar, 1u, __ATOMIC_RELAXED, __HIP_MEMORY_SCOPE_AGENT);
        unsigned tgt = 16u * (unsigned)(t + 1);
        while (__hip_atomic_load(bar, __ATOMIC_RELAXED, __HIP_MEMORY_SCOPE_AGENT) < tgt)
          __builtin_amdgcn_s_sleep(1);
      }
      __builtin_amdgcn_s_barrier();
    }
  }
}

// ---------------------------------------------------------------------------
extern "C" void kernel_launch(void* const* d_in, const int* in_sizes, int n_in,
                              void* d_out, int out_size, void* d_ws, size_t ws_size,
                              hipStream_t stream)
{
  const float* inputs = (const float*)d_in[0];
  // d_in[1..3] = W_e_w, W_e_b, U_e_w : dead (softmax of constant row)
  const float* w_ih = (const float*)d_in[4];
  const float* w_hh = (const float*)d_in[5];
  const float* b_ih = (const float*)d_in[6];
  const float* b_hh = (const float*)d_in[7];
  float* out = (float*)d_out;
  char* ws = (char*)d_ws;

  const size_t xg_f32_bytes = (size_t)32768 * 2048 * 4;
  const size_t xg_bf_bytes  = (size_t)32768 * 2048 * 2;
  const size_t xbytes = (size_t)16777216 * 2;
  const size_t wbytes = (size_t)1048576 * 2;
  const size_t biasb  = 2048 * 4;
  const size_t hbytes = (size_t)2 * 128 * 512 * 2;
  const size_t barb   = 512;
  const size_t tail = xbytes + wbytes + biasb + hbytes + barb + 1024;

  bool f32p = ws_size >= xg_f32_bytes + tail;
  size_t xgb  = f32p ? xg_f32_bytes : xg_bf_bytes;
  size_t oX   = xgb;
  size_t oW   = oX + xbytes;
  size_t oB   = oW + wbytes;
  size_t oH   = (oB + biasb + 255) & ~(size_t)255;
  size_t oBar = oH + hbytes;

  hipMemsetAsync(ws + oH, 0, hbytes + barb, stream);

  convert_kernel<<<2048, 256, 0, stream>>>(inputs, w_ih, b_ih, b_hh,
      (ushort_t*)(ws + oX), (ushort_t*)(ws + oW), (float*)(ws + oB));

  if (f32p) {
    gemm_xg_kernel<false><<<4096, 256, 0, stream>>>(
        (const ushort_t*)(ws + oX), (const ushort_t*)(ws + oW), (const float*)(ws + oB), ws);
    lstm_rec_kernel<false><<<64, 256, 0, stream>>>(
        w_hh, ws, (ushort_t*)(ws + oH), out, (unsigned*)(ws + oBar));
  } else {
    gemm_xg_kernel<true><<<4096, 256, 0, stream>>>(
        (const ushort_t*)(ws + oX), (const ushort_t*)(ws + oW), (const float*)(ws + oB), ws);
    lstm_rec_kernel<true><<<64, 256, 0, stream>>>(
        w_hh, ws, (ushort_t*)(ws + oH), out, (unsigned*)(ws + oBar));
  }
  (void)in_sizes; (void)n_in; (void)out_size;
}